// Round 2
// baseline (671.736 us; speedup 1.0000x reference)
//
#include <hip/hip_runtime.h>
#include <math.h>

#define LSEQ 2304
#define DM 128
#define DI 256
#define DS 16
#define RK 8
#define NCH 576     // 4-row chunks
#define CLEN 4
#define NG 8        // carry groups
#define GS 72       // chunks per group (NG*GS == NCH)
#define NSI (DI*DS) // 4096 state indices
#define TROWS 8     // rows per front tile
#define NT (LSEQ/TROWS) // 288 tiles
#define EPSF 1e-5f

__device__ __forceinline__ float silu_f(float s) { return s / (1.f + __expf(-s)); }
__device__ __forceinline__ float softplus_f(float x) { return (x > 20.f) ? x : log1pf(__expf(x)); }

// ---------------------------------------------------------------------------
// FRONT: fused in-proj GEMM + conv4 + silu + xproj + dt + chunk scan.
// grid (288, 2): 8-row x 256-ch tiles.
//   y=0: xi GEMM (11-row halo in registers) -> conv -> silu -> xc (LDS+global)
//        -> xproj (2 chunks) -> dt -> chunk-local scan -> S, dts, dbl.
//   y=1: z GEMM -> silu -> sz.
// block 256 = one thread per output channel d.
template<bool FIRST>
__global__ __launch_bounds__(256, 4)
void k_front(const float* __restrict__ seq, const float* __restrict__ x0,
             const float* __restrict__ Wi,
             const float* __restrict__ cw, const float* __restrict__ cbias,
             const float* __restrict__ Wx,
             const float* __restrict__ Wdt, const float* __restrict__ bdt,
             const float* __restrict__ Alog,
             float* __restrict__ xc_g, float* __restrict__ sz_g,
             float* __restrict__ dbl_g, float* __restrict__ dts_g,
             float* __restrict__ S) {
    __shared__ float As[11 * 128];       // seq rows l0-3 .. l0+7
    __shared__ float xcs[TROWS * 256];
    __shared__ float part[2 * 4 * 160];  // [q][kc][o]
    __shared__ float dtrs[TROWS * 8];
    __shared__ float dbls[TROWS * 32];

    const int tile = blockIdx.x;
    const int l0 = tile * TROWS;
    const bool isZ = blockIdx.y == 1;
    const int tid = threadIdx.x;
    const int d = tid;

    if (FIRST) {
        const int rlo = isZ ? 3 : 0;
        for (int idx = tid + rlo * 128; idx < 11 * 128; idx += 256) {
            const int r = idx >> 7, cc = idx & 127;
            const int l = l0 - 3 + r;
            As[idx] = (l >= 0) ? x0[cc * LSEQ + l] : 0.f;
        }
    } else if (!isZ) {
        // 11 rows x 32 float4
        for (int idx = tid; idx < 11 * 32; idx += 256) {
            const int r = idx >> 5, cq = (idx & 31) * 4;
            const int l = l0 - 3 + r;
            const float4 v = (l >= 0) ? *(const float4*)&seq[l * DM + cq]
                                      : make_float4(0.f, 0.f, 0.f, 0.f);
            *(float4*)&As[r * 128 + cq] = v;
        }
    } else {
        // z needs rows 3..10 only: 8 rows x 32 float4
        for (int idx = tid; idx < 8 * 32; idx += 256) {
            const int r = 3 + (idx >> 5), cq = (idx & 31) * 4;
            *(float4*)&As[r * 128 + cq] =
                *(const float4*)&seq[(l0 - 3 + r) * DM + cq];
        }
    }
    __syncthreads();

    if (isZ) {
        float az[8];
#pragma unroll
        for (int r = 0; r < 8; ++r) az[r] = 0.f;
        for (int k4 = 0; k4 < 32; ++k4) {
            float bv[4];
#pragma unroll
            for (int u = 0; u < 4; ++u) bv[u] = Wi[(k4 * 4 + u) * 512 + 256 + d];
#pragma unroll
            for (int r = 0; r < 8; ++r) {
                const float4 a4 = *(const float4*)&As[(r + 3) * 128 + k4 * 4];
                az[r] += a4.x * bv[0] + a4.y * bv[1] + a4.z * bv[2] + a4.w * bv[3];
            }
        }
#pragma unroll
        for (int rr = 0; rr < 8; ++rr)
            sz_g[(l0 + rr) * DI + d] = silu_f(az[rr]);
        return;
    }

    // ---- x path: xi GEMM with 3-row halo in registers ----
    float ax[11];
#pragma unroll
    for (int r = 0; r < 11; ++r) ax[r] = 0.f;
    for (int k4 = 0; k4 < 32; ++k4) {
        float bv[4];
#pragma unroll
        for (int u = 0; u < 4; ++u) bv[u] = Wi[(k4 * 4 + u) * 512 + d];
#pragma unroll
        for (int r = 0; r < 11; ++r) {
            const float4 a4 = *(const float4*)&As[r * 128 + k4 * 4];
            ax[r] += a4.x * bv[0] + a4.y * bv[1] + a4.z * bv[2] + a4.w * bv[3];
        }
    }
    {
        const float w0 = cw[d * 4 + 0], w1 = cw[d * 4 + 1];
        const float w2 = cw[d * 4 + 2], w3 = cw[d * 4 + 3];
        const float cbv = cbias[d];
#pragma unroll
        for (int rr = 0; rr < 8; ++rr) {
            const float v = silu_f(cbv + w0 * ax[rr] + w1 * ax[rr + 1] +
                                   w2 * ax[rr + 2] + w3 * ax[rr + 3]);
            xcs[rr * 256 + d] = v;
            xc_g[(l0 + rr) * DI + d] = v;
        }
    }
    __syncthreads();

    // ---- xproj: 2 chunks x 160 outputs x 4 K-quarters = 1280 tasks ----
    for (int task = tid; task < 1280; task += 256) {
        const int q = task / 640;
        const int rem = task - q * 640;
        const int kc = rem / 160;
        const int o = rem - kc * 160;
        const int r = o / 40, j = o - r * 40;
        const float* xr = &xcs[(q * 4 + r) * 256 + kc * 64];
        const float* wp = &Wx[(kc * 64) * 40 + j];
        float acc = 0.f;
#pragma unroll 8
        for (int k = 0; k < 64; ++k) acc += xr[k] * wp[k * 40];
        part[(q * 4 + kc) * 160 + o] = acc;
    }
    __syncthreads();
    for (int idx = tid; idx < 320; idx += 256) {
        const int q = idx / 160, o = idx - q * 160;
        const float acc = part[(q * 4 + 0) * 160 + o] + part[(q * 4 + 1) * 160 + o] +
                          part[(q * 4 + 2) * 160 + o] + part[(q * 4 + 3) * 160 + o];
        const int r = o / 40, j = o - r * 40;
        dbl_g[(l0 + q * 4 + r) * 40 + j] = acc;
        if (j < RK) dtrs[(q * 4 + r) * 8 + j] = acc;
        else        dbls[(q * 4 + r) * 32 + (j - 8)] = acc;
    }
    __syncthreads();

    // ---- dt + chunk-local scan (thread d holds 16 states) ----
    float wdt[8];
#pragma unroll
    for (int q8 = 0; q8 < 8; ++q8) wdt[q8] = Wdt[q8 * DI + d];
    const float bdv = bdt[d];
    float A[16];
#pragma unroll
    for (int v = 0; v < 4; ++v) {
        const float4 a4 = *(const float4*)&Alog[d * DS + v * 4];
        A[v * 4 + 0] = -__expf(a4.x);
        A[v * 4 + 1] = -__expf(a4.y);
        A[v * 4 + 2] = -__expf(a4.z);
        A[v * 4 + 3] = -__expf(a4.w);
    }
#pragma unroll
    for (int q = 0; q < 2; ++q) {
        const int c = tile * 2 + q;
        float dtv[CLEN], xcv[CLEN];
#pragma unroll
        for (int r = 0; r < CLEN; ++r) {
            float acc = bdv;
#pragma unroll
            for (int k = 0; k < 8; ++k) acc += dtrs[(q * 4 + r) * 8 + k] * wdt[k];
            dtv[r] = softplus_f(acc);
            xcv[r] = xcs[(q * 4 + r) * 256 + d];
        }
        dts_g[c * DI + d] = dtv[0] + dtv[1] + dtv[2] + dtv[3];

        float hs[16];
#pragma unroll
        for (int s = 0; s < 16; ++s) hs[s] = 0.f;
#pragma unroll
        for (int t = 0; t < CLEN; ++t) {
            const float dtt = dtv[t];
            const float uv = dtt * xcv[t];
            const float* Brow = &dbls[(q * 4 + t) * 32];
#pragma unroll
            for (int s = 0; s < 16; ++s) {
                const float e = __expf(dtt * A[s]);
                hs[s] = e * hs[s] + uv * Brow[s];
            }
        }
        const int base = c * NSI + d * DS;
#pragma unroll
        for (int v = 0; v < 4; ++v) {
            *(float4*)&S[base + v * 4] =
                make_float4(hs[v * 4], hs[v * 4 + 1], hs[v * 4 + 2], hs[v * 4 + 3]);
        }
    }
}

// ---------------------------------------------------------------------------
// CARRY: per group of GS=72 chunks, in place: S -> within-group carry INTO
// each chunk. Decay reconstructed as exp(A*dts); exclusive prefix dt-sums to
// dtspre; group aggregates (Pg, Sg) out. grid (NG, 16); block 256.
__global__ __launch_bounds__(256, 4)
void k_carry(float* __restrict__ S, const float* __restrict__ dts,
             const float* __restrict__ Alog,
             float* __restrict__ dtspre,
             float* __restrict__ Pg, float* __restrict__ Sg) {
    const int g = blockIdx.x;
    const int i = blockIdx.y * 256 + threadIdx.x;
    const int d = i >> 4;
    const float Av = -__expf(Alog[i]);   // Alog laid out [d][s] == [i]
    float G = 0.f, cd = 0.f;
    const int c0 = g * GS;
    const int base = c0 * NSI + i;
#pragma unroll 8
    for (int k = 0; k < GS; ++k) {
        const int idx = base + k * NSI;
        const float dtsv = dts[(c0 + k) * DI + d];
        if ((i & 15) == 0) dtspre[(c0 + k) * DI + d] = cd;  // exclusive prefix
        const float p = __expf(Av * dtsv);
        const float s = S[idx];
        S[idx] = G;
        G = p * G + s;
        cd += dtsv;
    }
    Pg[g * NSI + i] = __expf(Av * cd);
    Sg[g * NSI + i] = G;
}

// ---------------------------------------------------------------------------
// TAIL: cross-group carry by <=NG-1 lookback over (Pg,Sg); h0 = Sloc +
// exp(A*dtspre)*Gc; dt recomputed from dbl; re-scan + gate + out-GEMM
// (K-split x4) + rmsnorm. grid 576; block 256.
template<bool LAST>
__global__ __launch_bounds__(256, 3)
void k_tail(const float* __restrict__ xc_g, const float* __restrict__ dbl_g,
            const float* __restrict__ Alog, const float* __restrict__ Sloc,
            const float* __restrict__ dtspre,
            const float* __restrict__ Pg, const float* __restrict__ Sg,
            const float* __restrict__ Dp, const float* __restrict__ sz_g,
            const float* __restrict__ Wdt, const float* __restrict__ bdt,
            const float* __restrict__ Wo, const float* __restrict__ rmsw,
            float* __restrict__ seq, float* __restrict__ out) {
    __shared__ float dbls[CLEN * 40];     // full 40-wide rows (dtr|B|C)
    __shared__ float Ys[CLEN * 256];
    __shared__ float partO[4 * CLEN * 128];   // [kg][r][cc]
    __shared__ float Os[CLEN * 129];
    __shared__ float red[CLEN * 32];
    __shared__ float scaleS[CLEN];
    const int c = blockIdx.x;
    const int g = c / GS;
    const int l0 = c * CLEN;
    const int tid = threadIdx.x;
    const int d = tid;

    if (tid < CLEN * 40) dbls[tid] = dbl_g[l0 * 40 + tid];

    float A[16], h[16];
#pragma unroll
    for (int v = 0; v < 4; ++v) {
        const float4 a4 = *(const float4*)&Alog[d * DS + v * 4];
        A[v * 4 + 0] = -__expf(a4.x);
        A[v * 4 + 1] = -__expf(a4.y);
        A[v * 4 + 2] = -__expf(a4.z);
        A[v * 4 + 3] = -__expf(a4.w);
    }
    // cross-group carry: serial fold over groups 0..g-1 (order matters)
#pragma unroll
    for (int s = 0; s < 16; ++s) h[s] = 0.f;
    for (int gp = 0; gp < g; ++gp) {
#pragma unroll
        for (int v = 0; v < 4; ++v) {
            const float4 p4 = *(const float4*)&Pg[gp * NSI + d * DS + v * 4];
            const float4 s4 = *(const float4*)&Sg[gp * NSI + d * DS + v * 4];
            h[v * 4 + 0] = p4.x * h[v * 4 + 0] + s4.x;
            h[v * 4 + 1] = p4.y * h[v * 4 + 1] + s4.y;
            h[v * 4 + 2] = p4.z * h[v * 4 + 2] + s4.z;
            h[v * 4 + 3] = p4.w * h[v * 4 + 3] + s4.w;
        }
    }
    // h0 = Sloc(within-group carry) + exp(A*cdts) * Gc
    const float cdts = dtspre[c * DI + d];
#pragma unroll
    for (int v = 0; v < 4; ++v) {
        const float4 s4 = *(const float4*)&Sloc[c * NSI + d * DS + v * 4];
        h[v * 4 + 0] = s4.x + __expf(A[v * 4 + 0] * cdts) * h[v * 4 + 0];
        h[v * 4 + 1] = s4.y + __expf(A[v * 4 + 1] * cdts) * h[v * 4 + 1];
        h[v * 4 + 2] = s4.z + __expf(A[v * 4 + 2] * cdts) * h[v * 4 + 2];
        h[v * 4 + 3] = s4.w + __expf(A[v * 4 + 3] * cdts) * h[v * 4 + 3];
    }
    float xcv[CLEN], szv[CLEN];
#pragma unroll
    for (int r = 0; r < CLEN; ++r) {
        xcv[r] = xc_g[(l0 + r) * DI + d];
        szv[r] = sz_g[(l0 + r) * DI + d];
    }
    const float dskip = Dp[d];
    __syncthreads();

    // dt = softplus(dtr @ Wdt + bdt) — identical arithmetic to k_front
    float dtv[CLEN];
    {
        float wdt[8];
#pragma unroll
        for (int q = 0; q < 8; ++q) wdt[q] = Wdt[q * DI + d];
        const float bdv = bdt[d];
#pragma unroll
        for (int r = 0; r < CLEN; ++r) {
            float acc = bdv;
#pragma unroll
            for (int q = 0; q < 8; ++q) acc += dbls[r * 40 + q] * wdt[q];
            dtv[r] = softplus_f(acc);
        }
    }
#pragma unroll
    for (int t = 0; t < CLEN; ++t) {
        const float dtt = dtv[t];
        const float uv = dtt * xcv[t];
        const float* Brow = &dbls[t * 40 + 8];
        const float* Crow = &dbls[t * 40 + 24];
        float sum = 0.f;
#pragma unroll
        for (int s = 0; s < 16; ++s) {
            const float e = __expf(dtt * A[s]);
            h[s] = e * h[s] + uv * Brow[s];
            sum += h[s] * Crow[s];
        }
        Ys[t * 256 + d] = (sum + dskip * xcv[t]) * szv[t];
    }
    __syncthreads();

    // out-GEMM: 64 cc-pairs x 4 K-groups (K=64 each), float2 Wo loads
    {
        const int ccp = tid & 63;
        const int kg = tid >> 6;
        float acc[CLEN][2];
#pragma unroll
        for (int r = 0; r < CLEN; ++r) { acc[r][0] = 0.f; acc[r][1] = 0.f; }
        const float* wp = &Wo[(kg * 64) * DM + ccp * 2];
        const float* yp = &Ys[kg * 64];
#pragma unroll 8
        for (int k = 0; k < 64; ++k) {
            const float2 w2 = *(const float2*)(wp + k * DM);
#pragma unroll
            for (int r = 0; r < CLEN; ++r) {
                const float yv = yp[r * 256 + k];
                acc[r][0] += yv * w2.x;
                acc[r][1] += yv * w2.y;
            }
        }
#pragma unroll
        for (int r = 0; r < CLEN; ++r) {
            partO[(kg * CLEN + r) * 128 + ccp * 2 + 0] = acc[r][0];
            partO[(kg * CLEN + r) * 128 + ccp * 2 + 1] = acc[r][1];
        }
        __syncthreads();
        for (int idx = tid; idx < CLEN * 128; idx += 256) {
            const int r = idx >> 7, cc = idx & 127;
            Os[r * 129 + cc] = partO[(0 * CLEN + r) * 128 + cc] +
                               partO[(1 * CLEN + r) * 128 + cc] +
                               partO[(2 * CLEN + r) * 128 + cc] +
                               partO[(3 * CLEN + r) * 128 + cc];
        }
        __syncthreads();
    }

    // rmsnorm + store
    if (tid < CLEN * 32) {
        const int r = tid >> 5, part = tid & 31;
        float ss = 0.f;
#pragma unroll
        for (int i = 0; i < 4; ++i) {
            const float v = Os[r * 129 + part * 4 + i];
            ss += v * v;
        }
        red[tid] = ss;
    }
    __syncthreads();
    if (tid < CLEN) {
        float ss = 0.f;
#pragma unroll
        for (int p = 0; p < 32; ++p) ss += red[tid * 32 + p];
        scaleS[tid] = rsqrtf(ss * (1.f / DM) + EPSF);
    }
    __syncthreads();
    if (LAST) {
        for (int idx = tid; idx < CLEN * DM; idx += 256) {
            const int r = idx >> 7, cc = idx & 127;
            out[cc * LSEQ + (l0 + r)] = Os[r * 129 + cc] * scaleS[r] * rmsw[cc];
        }
    } else {
        for (int idx = tid; idx < CLEN * DM; idx += 256) {
            const int r = idx >> 7, cc = idx & 127;
            seq[(l0 + r) * DM + cc] = Os[r * 129 + cc] * scaleS[r] * rmsw[cc];
        }
    }
}

// ---------------------------------------------------------------------------
extern "C" void kernel_launch(void* const* d_in, const int* in_sizes, int n_in,
                              void* d_out, int out_size, void* d_ws, size_t ws_size,
                              hipStream_t stream) {
    const float* x    = (const float*)d_in[0];
    const float* W_in = (const float*)d_in[1];
    const float* cw   = (const float*)d_in[2];
    const float* cb   = (const float*)d_in[3];
    const float* Wx   = (const float*)d_in[4];
    const float* Wdt  = (const float*)d_in[5];
    const float* bdt  = (const float*)d_in[6];
    const float* Alog = (const float*)d_in[7];
    const float* Dp   = (const float*)d_in[8];
    const float* Wo   = (const float*)d_in[9];
    const float* rmsw = (const float*)d_in[10];
    float* out = (float*)d_out;

    float* ws      = (float*)d_ws;
    float* seq     = ws; ws += LSEQ * DM;
    float* szb     = ws; ws += LSEQ * DI;
    float* xcb     = ws; ws += LSEQ * DI;
    float* dblb    = ws; ws += LSEQ * 40;
    float* dtsb    = ws; ws += NCH * DI;
    float* dtspreb = ws; ws += NCH * DI;
    float* Sb      = ws; ws += NCH * NSI;
    float* Pgb     = ws; ws += NG * NSI;
    float* Sgb     = ws; ws += NG * NSI;

    for (int layer = 0; layer < 8; ++layer) {
        const float* Wi_l   = W_in + (size_t)layer * DM * 512;
        const float* cw_l   = cw   + (size_t)layer * DI * 4;
        const float* cb_l   = cb   + (size_t)layer * DI;
        const float* Wx_l   = Wx   + (size_t)layer * DI * 40;
        const float* Wdt_l  = Wdt  + (size_t)layer * RK * DI;
        const float* bdt_l  = bdt  + (size_t)layer * DI;
        const float* Alog_l = Alog + (size_t)layer * DI * DS;
        const float* Dp_l   = Dp   + (size_t)layer * DI;
        const float* Wo_l   = Wo   + (size_t)layer * DI * DM;
        const float* rmsw_l = rmsw + (size_t)layer * DM;

        if (layer == 0)
            k_front<true><<<dim3(NT, 2), 256, 0, stream>>>(seq, x, Wi_l, cw_l, cb_l,
                                                           Wx_l, Wdt_l, bdt_l, Alog_l,
                                                           xcb, szb, dblb, dtsb, Sb);
        else
            k_front<false><<<dim3(NT, 2), 256, 0, stream>>>(seq, x, Wi_l, cw_l, cb_l,
                                                            Wx_l, Wdt_l, bdt_l, Alog_l,
                                                            xcb, szb, dblb, dtsb, Sb);

        k_carry<<<dim3(NG, 16), 256, 0, stream>>>(Sb, dtsb, Alog_l,
                                                  dtspreb, Pgb, Sgb);

        if (layer == 7)
            k_tail<true><<<NCH, 256, 0, stream>>>(xcb, dblb, Alog_l, Sb, dtspreb,
                                                  Pgb, Sgb, Dp_l, szb, Wdt_l, bdt_l,
                                                  Wo_l, rmsw_l, seq, out);
        else
            k_tail<false><<<NCH, 256, 0, stream>>>(xcb, dblb, Alog_l, Sb, dtspreb,
                                                   Pgb, Sgb, Dp_l, szb, Wdt_l, bdt_l,
                                                   Wo_l, rmsw_l, seq, out);
    }
}